// Round 1
// baseline (603.186 us; speedup 1.0000x reference)
//
#include <hip/hip_runtime.h>
#include <math.h>

#define TH 65536
#define SD 128
#define AD 8
#define HD 256

constexpr float GAMMA  = 0.99f;
constexpr float LMBDA  = 0.95f;
constexpr float EPSC   = 0.2f;
constexpr float VFC    = 0.5f;
constexpr float ENTC   = 0.01f;
constexpr float LOG2PI = 1.8378770664093453f;

// workspace layout (float offsets)
constexpr size_t WS_VALUES = 0;        // TH+1 floats (values + v_last)
constexpr size_t WS_ADV    = 65540;    // TH floats, unnormalized advantages
constexpr size_t WS_DELTA  = 131080;   // TH floats
constexpr size_t WS_CHP    = 196620;   // 64
constexpr size_t WS_CHB    = 196684;   // 64
constexpr size_t WS_CARRY  = 196748;   // 64
constexpr size_t WS_SCAL   = 196812;   // [0]=sum_adv [1]=sumsq_adv [2]=vf_sum [3]=pg_sum

__global__ __launch_bounds__(64) void zero_scal_kernel(float* __restrict__ scal) {
    if (threadIdx.x < 4) scal[threadIdx.x] = 0.f;
}

// ---------------- fused value-MLP:  values = tanh(tanh(X@W1+b1)@W2+b2)@wh + bh
__global__ __launch_bounds__(256) void mlp_v_kernel(
    const float* __restrict__ X, int nrows,
    const float* __restrict__ W1, const float* __restrict__ b1,
    const float* __restrict__ W2, const float* __restrict__ b2,
    const float* __restrict__ wh, const float* __restrict__ bh,
    float* __restrict__ outv)
{
    __shared__ float xs[32 * SD];   // 16 KB
    __shared__ float h1[32 * HD];   // 32 KB
    const int tid = threadIdx.x;
    const int tx = tid & 31, ty = tid >> 5;
    const int row0 = blockIdx.x * 32;

    // stage X tile (32 rows x 128)
#pragma unroll
    for (int i = 0; i < 4; ++i) {
        int idx = tid + i * 256;          // float4 index
        int rr = idx >> 5, c4 = idx & 31;
        float4 v = make_float4(0.f, 0.f, 0.f, 0.f);
        if (row0 + rr < nrows)
            v = *(const float4*)(X + (size_t)(row0 + rr) * SD + c4 * 4);
        *(float4*)(xs + rr * SD + c4 * 4) = v;
    }
    __syncthreads();

    const int n0 = tx * 8;
    float acc[4][8];
#pragma unroll
    for (int i = 0; i < 4; ++i)
#pragma unroll
        for (int j = 0; j < 8; ++j) acc[i][j] = 0.f;

    // layer 1: K = 128
    for (int k = 0; k < SD; ++k) {
        float4 wa = *(const float4*)(W1 + k * HD + n0);
        float4 wb = *(const float4*)(W1 + k * HD + n0 + 4);
        float w[8] = {wa.x, wa.y, wa.z, wa.w, wb.x, wb.y, wb.z, wb.w};
#pragma unroll
        for (int i = 0; i < 4; ++i) {
            float xv = xs[(ty * 4 + i) * SD + k];
#pragma unroll
            for (int j = 0; j < 8; ++j) acc[i][j] = fmaf(xv, w[j], acc[i][j]);
        }
    }
#pragma unroll
    for (int i = 0; i < 4; ++i)
#pragma unroll
        for (int j = 0; j < 8; ++j)
            h1[(ty * 4 + i) * HD + n0 + j] = tanhf(acc[i][j] + b1[n0 + j]);
    __syncthreads();

#pragma unroll
    for (int i = 0; i < 4; ++i)
#pragma unroll
        for (int j = 0; j < 8; ++j) acc[i][j] = 0.f;

    // layer 2: K = 256
    for (int k = 0; k < HD; ++k) {
        float4 wa = *(const float4*)(W2 + k * HD + n0);
        float4 wb = *(const float4*)(W2 + k * HD + n0 + 4);
        float w[8] = {wa.x, wa.y, wa.z, wa.w, wb.x, wb.y, wb.z, wb.w};
#pragma unroll
        for (int i = 0; i < 4; ++i) {
            float xv = h1[(ty * 4 + i) * HD + k];
#pragma unroll
            for (int j = 0; j < 8; ++j) acc[i][j] = fmaf(xv, w[j], acc[i][j]);
        }
    }

    // value head: dot(tanh(h2), wh) per row; reduce across the 32 tx lanes
    float part[4];
#pragma unroll
    for (int i = 0; i < 4; ++i) {
        float p = 0.f;
#pragma unroll
        for (int j = 0; j < 8; ++j)
            p += tanhf(acc[i][j] + b2[n0 + j]) * wh[n0 + j];
        part[i] = p;
    }
#pragma unroll
    for (int off = 16; off >= 1; off >>= 1)
#pragma unroll
        for (int i = 0; i < 4; ++i)
            part[i] += __shfl_down(part[i], off, 32);
    if (tx == 0) {
        float bb = bh[0];
#pragma unroll
        for (int i = 0; i < 4; ++i) {
            int rr = row0 + ty * 4 + i;
            if (rr < nrows) outv[rr] = part[i] + bb;
        }
    }
}

// ---------------- GAE phase 1: per-chunk affine composition + deltas
__global__ __launch_bounds__(256) void gae_chunk_kernel(
    const float* __restrict__ rw, const float* __restrict__ m,
    const float* __restrict__ values, float* __restrict__ delta_out,
    float* __restrict__ chunkP, float* __restrict__ chunkB)
{
    __shared__ float sp_[256], sb_[256];
    const int j = threadIdx.x;
    const int t0 = blockIdx.x * 1024 + j * 4;

    float4 vv = *(const float4*)(values + t0);
    float v4 = values[t0 + 4];
    float4 rr = *(const float4*)(rw + t0);
    float4 mm = *(const float4*)(m + t0);
    float vs[5] = {vv.x, vv.y, vv.z, vv.w, v4};
    float rs[4] = {rr.x, rr.y, rr.z, rr.w};
    float ms[4] = {mm.x, mm.y, mm.z, mm.w};
    float d[4];
#pragma unroll
    for (int i = 0; i < 4; ++i)
        d[i] = rs[i] + GAMMA * vs[i + 1] * ms[i] - vs[i];
    *(float4*)(delta_out + t0) = make_float4(d[0], d[1], d[2], d[3]);

    const float g = GAMMA * LMBDA;
    float P = 1.f, B = 0.f;
#pragma unroll
    for (int i = 3; i >= 0; --i) {   // F = f_t ∘ F  (t descending)
        float p = g * ms[i];
        B = d[i] + p * B;
        P = p * P;
    }
    sp_[j] = P; sb_[j] = B;
    __syncthreads();
    // inclusive suffix scan (Hillis-Steele), composition (Pj*Pk, Bj + Pj*Bk)
    for (int dstep = 1; dstep < 256; dstep <<= 1) {
        float pj = sp_[j], bj = sb_[j], pk = 1.f, bk = 0.f;
        if (j + dstep < 256) { pk = sp_[j + dstep]; bk = sb_[j + dstep]; }
        __syncthreads();
        sp_[j] = pj * pk;
        sb_[j] = bj + pj * bk;
        __syncthreads();
    }
    if (j == 0) { chunkP[blockIdx.x] = sp_[0]; chunkB[blockIdx.x] = sb_[0]; }
}

// ---------------- GAE phase 2: serial carry over the 64 chunks
__global__ __launch_bounds__(64) void gae_carry_kernel(
    const float* __restrict__ chunkP, const float* __restrict__ chunkB,
    float* __restrict__ carry)
{
    if (threadIdx.x == 0) {
        float A = 0.f;
        for (int c = 63; c >= 0; --c) {
            carry[c] = A;               // A at right edge of chunk c
            A = chunkB[c] + chunkP[c] * A;
        }
    }
}

// ---------------- GAE phase 3: apply carries, emit adv + reductions
__global__ __launch_bounds__(256) void gae_apply_kernel(
    const float* __restrict__ m, const float* __restrict__ delta,
    const float* __restrict__ carry,
    float* __restrict__ adv_out, float* __restrict__ scal)
{
    __shared__ float sp_[256], sb_[256];
    __shared__ float red[12];
    const int j = threadIdx.x;
    const int t0 = blockIdx.x * 1024 + j * 4;

    float4 dd = *(const float4*)(delta + t0);
    float4 mm = *(const float4*)(m + t0);
    float ds[4] = {dd.x, dd.y, dd.z, dd.w};
    float ms[4] = {mm.x, mm.y, mm.z, mm.w};
    const float g = GAMMA * LMBDA;

    float P = 1.f, B = 0.f;
#pragma unroll
    for (int i = 3; i >= 0; --i) {
        float p = g * ms[i];
        B = ds[i] + p * B;
        P = p * P;
    }
    sp_[j] = P; sb_[j] = B;
    __syncthreads();
    for (int dstep = 1; dstep < 256; dstep <<= 1) {
        float pj = sp_[j], bj = sb_[j], pk = 1.f, bk = 0.f;
        if (j + dstep < 256) { pk = sp_[j + dstep]; bk = sb_[j + dstep]; }
        __syncthreads();
        sp_[j] = pj * pk;
        sb_[j] = bj + pj * bk;
        __syncthreads();
    }
    float Pe = 1.f, Be = 0.f;
    if (j < 255) { Pe = sp_[j + 1]; Be = sb_[j + 1]; }
    float A = Be + Pe * carry[blockIdx.x];   // A at t0+4

    float s1 = 0.f, s2 = 0.f, vf = 0.f;
    float a4[4];
#pragma unroll
    for (int i = 3; i >= 0; --i) {
        A = ds[i] + g * ms[i] * A;
        a4[i] = A;
        float ab = fabsf(A);
        vf += (ab < 1.f) ? 0.5f * A * A : ab - 0.5f;  // huber(-adv) == huber(adv)
        s1 += A;
        s2 += A * A;
    }
    *(float4*)(adv_out + t0) = make_float4(a4[0], a4[1], a4[2], a4[3]);

#pragma unroll
    for (int off = 32; off >= 1; off >>= 1) {
        s1 += __shfl_down(s1, off, 64);
        s2 += __shfl_down(s2, off, 64);
        vf += __shfl_down(vf, off, 64);
    }
    if ((j & 63) == 0) {
        int w = j >> 6;
        red[w] = s1; red[4 + w] = s2; red[8 + w] = vf;
    }
    __syncthreads();
    if (j == 0) {
        atomicAdd(&scal[0], red[0] + red[1] + red[2] + red[3]);
        atomicAdd(&scal[1], red[4] + red[5] + red[6] + red[7]);
        atomicAdd(&scal[2], red[8] + red[9] + red[10] + red[11]);
    }
}

// ---------------- fused policy-MLP + clipped PG loss
__global__ __launch_bounds__(256) void mlp_pi_kernel(
    const float* __restrict__ X,
    const float* __restrict__ W1, const float* __restrict__ b1,
    const float* __restrict__ W2, const float* __restrict__ b2,
    const float* __restrict__ muW, const float* __restrict__ mub,
    const float* __restrict__ logstd,
    const float* __restrict__ act, const float* __restrict__ lpold,
    const float* __restrict__ adv, float* __restrict__ scal)
{
    __shared__ float xs[32 * SD];
    __shared__ float h1[32 * HD];
    __shared__ float red[4];
    const int tid = threadIdx.x;
    const int tx = tid & 31, ty = tid >> 5;
    const int row0 = blockIdx.x * 32;

#pragma unroll
    for (int i = 0; i < 4; ++i) {
        int idx = tid + i * 256;
        int rr = idx >> 5, c4 = idx & 31;
        float4 v = *(const float4*)(X + (size_t)(row0 + rr) * SD + c4 * 4);
        *(float4*)(xs + rr * SD + c4 * 4) = v;
    }
    __syncthreads();

    const int n0 = tx * 8;
    float acc[4][8];
#pragma unroll
    for (int i = 0; i < 4; ++i)
#pragma unroll
        for (int j = 0; j < 8; ++j) acc[i][j] = 0.f;

    for (int k = 0; k < SD; ++k) {
        float4 wa = *(const float4*)(W1 + k * HD + n0);
        float4 wb = *(const float4*)(W1 + k * HD + n0 + 4);
        float w[8] = {wa.x, wa.y, wa.z, wa.w, wb.x, wb.y, wb.z, wb.w};
#pragma unroll
        for (int i = 0; i < 4; ++i) {
            float xv = xs[(ty * 4 + i) * SD + k];
#pragma unroll
            for (int j = 0; j < 8; ++j) acc[i][j] = fmaf(xv, w[j], acc[i][j]);
        }
    }
#pragma unroll
    for (int i = 0; i < 4; ++i)
#pragma unroll
        for (int j = 0; j < 8; ++j)
            h1[(ty * 4 + i) * HD + n0 + j] = tanhf(acc[i][j] + b1[n0 + j]);
    __syncthreads();

#pragma unroll
    for (int i = 0; i < 4; ++i)
#pragma unroll
        for (int j = 0; j < 8; ++j) acc[i][j] = 0.f;

    for (int k = 0; k < HD; ++k) {
        float4 wa = *(const float4*)(W2 + k * HD + n0);
        float4 wb = *(const float4*)(W2 + k * HD + n0 + 4);
        float w[8] = {wa.x, wa.y, wa.z, wa.w, wb.x, wb.y, wb.z, wb.w};
#pragma unroll
        for (int i = 0; i < 4; ++i) {
            float xv = h1[(ty * 4 + i) * HD + k];
#pragma unroll
            for (int j = 0; j < 8; ++j) acc[i][j] = fmaf(xv, w[j], acc[i][j]);
        }
    }

    // mu head partials: pm[i][aj] over this thread's 8 columns
    float pm[4][8];
#pragma unroll
    for (int i = 0; i < 4; ++i)
#pragma unroll
        for (int aj = 0; aj < 8; ++aj) pm[i][aj] = 0.f;
#pragma unroll
    for (int i = 0; i < 4; ++i) {
#pragma unroll
        for (int j = 0; j < 8; ++j) {
            float hv = tanhf(acc[i][j] + b2[n0 + j]);
            const float* mw = muW + (size_t)(n0 + j) * AD;
#pragma unroll
            for (int aj = 0; aj < 8; ++aj)
                pm[i][aj] = fmaf(hv, mw[aj], pm[i][aj]);
        }
    }
#pragma unroll
    for (int off = 16; off >= 1; off >>= 1)
#pragma unroll
        for (int i = 0; i < 4; ++i)
#pragma unroll
            for (int aj = 0; aj < 8; ++aj)
                pm[i][aj] += __shfl_down(pm[i][aj], off, 32);

    const float ssum = scal[0], ssq = scal[1];
    const float meanA = ssum / (float)TH;
    const float varA = fmaxf((ssq - ssum * ssum / (float)TH) / (float)(TH - 1), 0.f);
    const float denom = sqrtf(varA) + 1e-8f;

    float pg_local = 0.f;
    if (tx == 0) {
#pragma unroll
        for (int i = 0; i < 4; ++i) {
            int rr = row0 + ty * 4 + i;
            const float* arow = act + (size_t)rr * AD;
            float lp = 0.f;
#pragma unroll
            for (int aj = 0; aj < 8; ++aj) {
                float ls = logstd[aj];
                float mu = pm[i][aj] + mub[aj];
                float z = (arow[aj] - mu) * expf(-ls);
                lp += -0.5f * z * z - ls;
            }
            lp -= 4.f * LOG2PI;   // 8 * 0.5 * log(2pi)
            float ratio = expf(lp - lpold[rr]);
            float aN = (adv[rr] - meanA) / denom;
            float rc = fminf(fmaxf(ratio, 1.f - EPSC), 1.f + EPSC);
            pg_local -= fminf(ratio * aN, rc * aN);
        }
    }
#pragma unroll
    for (int off = 32; off >= 1; off >>= 1)
        pg_local += __shfl_down(pg_local, off, 64);
    if ((tid & 63) == 0) red[tid >> 6] = pg_local;
    __syncthreads();
    if (tid == 0) atomicAdd(&scal[3], red[0] + red[1] + red[2] + red[3]);
}

__global__ __launch_bounds__(64) void finalize_kernel(
    const float* __restrict__ scal, const float* __restrict__ logstd,
    float* __restrict__ out)
{
    if (threadIdx.x == 0) {
        float ls = 0.f;
        for (int j = 0; j < AD; ++j) ls += logstd[j];
        float entropy = 0.5f + 0.5f * LOG2PI + ls / (float)AD;
        out[0] = scal[3] / (float)TH + VFC * (scal[2] / (float)TH) - ENTC * entropy;
    }
}

extern "C" void kernel_launch(void* const* d_in, const int* in_sizes, int n_in,
                              void* d_out, int out_size, void* d_ws, size_t ws_size,
                              hipStream_t stream) {
    const float* s      = (const float*)d_in[0];
    const float* a      = (const float*)d_in[1];
    const float* r      = (const float*)d_in[2];
    const float* sp     = (const float*)d_in[3];
    const float* lpold  = (const float*)d_in[4];
    const float* dmask  = (const float*)d_in[5];
    const float* piW1   = (const float*)d_in[6];
    const float* pib1   = (const float*)d_in[7];
    const float* piW2   = (const float*)d_in[8];
    const float* pib2   = (const float*)d_in[9];
    const float* muW    = (const float*)d_in[10];
    const float* mub    = (const float*)d_in[11];
    const float* logstd = (const float*)d_in[12];
    const float* vW1    = (const float*)d_in[13];
    const float* vb1    = (const float*)d_in[14];
    const float* vW2    = (const float*)d_in[15];
    const float* vb2    = (const float*)d_in[16];
    const float* vhW    = (const float*)d_in[17];
    const float* vhb    = (const float*)d_in[18];

    float* ws      = (float*)d_ws;
    float* values  = ws + WS_VALUES;
    float* adv     = ws + WS_ADV;
    float* delta   = ws + WS_DELTA;
    float* chunkP  = ws + WS_CHP;
    float* chunkB  = ws + WS_CHB;
    float* carry   = ws + WS_CARRY;
    float* scal    = ws + WS_SCAL;

    zero_scal_kernel<<<1, 64, 0, stream>>>(scal);

    // values for all T rows of s, plus v_last from last row of sp
    mlp_v_kernel<<<TH / 32, 256, 0, stream>>>(s, TH, vW1, vb1, vW2, vb2, vhW, vhb, values);
    mlp_v_kernel<<<1, 256, 0, stream>>>(sp + (size_t)(TH - 1) * SD, 1,
                                        vW1, vb1, vW2, vb2, vhW, vhb, values + TH);

    gae_chunk_kernel<<<64, 256, 0, stream>>>(r, dmask, values, delta, chunkP, chunkB);
    gae_carry_kernel<<<1, 64, 0, stream>>>(chunkP, chunkB, carry);
    gae_apply_kernel<<<64, 256, 0, stream>>>(dmask, delta, carry, adv, scal);

    mlp_pi_kernel<<<TH / 32, 256, 0, stream>>>(s, piW1, pib1, piW2, pib2,
                                               muW, mub, logstd, a, lpold, adv, scal);

    finalize_kernel<<<1, 64, 0, stream>>>(scal, logstd, (float*)d_out);
}

// Round 2
// 408.095 us; speedup vs baseline: 1.4781x; 1.4781x over previous
//
#include <hip/hip_runtime.h>
#include <math.h>

#define TH 65536
#define SD 128
#define AD 8
#define HD 256

constexpr float GAMMA  = 0.99f;
constexpr float LMBDA  = 0.95f;
constexpr float EPSC   = 0.2f;
constexpr float VFC    = 0.5f;
constexpr float ENTC   = 0.01f;
constexpr float LOG2PI = 1.8378770664093453f;

typedef __attribute__((ext_vector_type(8))) short short8;
typedef __attribute__((ext_vector_type(4))) float f32x4;

// workspace layout (float offsets)
constexpr size_t WS_VALUES = 0;        // TH+1
constexpr size_t WS_ADV    = 65540;
constexpr size_t WS_DELTA  = 131080;
constexpr size_t WS_CHP    = 196620;
constexpr size_t WS_CHB    = 196684;
constexpr size_t WS_CARRY  = 196748;
constexpr size_t WS_SCAL   = 196812;   // [0]=sum [1]=sumsq [2]=vf [3]=pg
constexpr size_t WS_BF     = 196816;   // bf16 weight region (ushort units below)
// ushort offsets inside WS_BF region:
constexpr size_t SW_PIW1 = 0;          // 4*16*64*8  = 32768
constexpr size_t SW_PIW2 = 32768;      // 8*16*64*8  = 65536
constexpr size_t SW_VW1  = 98304;      // 32768
constexpr size_t SW_VW2  = 131072;     // 65536
constexpr size_t SW_MUW  = 196608;     // 8*1*64*8   = 4096

__device__ __forceinline__ unsigned short f2bf(float x) {
    unsigned int u = __float_as_uint(x);
    unsigned int r = (u + 0x7fffu + ((u >> 16) & 1u)) >> 16;
    return (unsigned short)r;
}

__global__ __launch_bounds__(64) void zero_scal_kernel(float* __restrict__ scal) {
    if (threadIdx.x < 4) scal[threadIdx.x] = 0.f;
}

// ------------- weight swizzle: f32 row-major [K][N] -> bf16 MFMA B-frag order
// frag id f: lane=f&63, grp=f>>6, nt=grp%NT, ks=grp/NT
// elem j: k = ks*32 + (lane>>4)*8 + j, n = nt*16 + (lane&15)
__global__ __launch_bounds__(256) void swizzle_kernel(
    const float* __restrict__ piW1, const float* __restrict__ vW1,
    const float* __restrict__ piW2, const float* __restrict__ vW2,
    const float* __restrict__ muW,
    unsigned short* __restrict__ dPiW1, unsigned short* __restrict__ dVW1,
    unsigned short* __restrict__ dPiW2, unsigned short* __restrict__ dVW2,
    unsigned short* __restrict__ dMuW)
{
    int fid = blockIdx.x * 256 + threadIdx.x;
    const float* S; unsigned short* D; int N, NT, lo, Nvalid;
    if      (fid <  4096) { S = piW1; D = dPiW1; N = 256; NT = 16; lo = 0;     Nvalid = 256; }
    else if (fid <  8192) { S = vW1;  D = dVW1;  N = 256; NT = 16; lo = 4096;  Nvalid = 256; }
    else if (fid < 16384) { S = piW2; D = dPiW2; N = 256; NT = 16; lo = 8192;  Nvalid = 256; }
    else if (fid < 24576) { S = vW2;  D = dVW2;  N = 256; NT = 16; lo = 16384; Nvalid = 256; }
    else if (fid < 25088) { S = muW;  D = dMuW;  N = 8;   NT = 1;  lo = 24576; Nvalid = 8;   }
    else return;
    int f = fid - lo;
    int lane = f & 63, grp = f >> 6;
    int nt = grp % NT, ks = grp / NT;
    int k0 = ks * 32 + ((lane >> 4) << 3);
    int n  = nt * 16 + (lane & 15);
    unsigned int u[4];
#pragma unroll
    for (int jj = 0; jj < 4; ++jj) {
        float v0 = (n < Nvalid) ? S[(size_t)(k0 + 2 * jj) * N + n]     : 0.f;
        float v1 = (n < Nvalid) ? S[(size_t)(k0 + 2 * jj + 1) * N + n] : 0.f;
        u[jj] = (unsigned int)f2bf(v0) | ((unsigned int)f2bf(v1) << 16);
    }
    ((uint4*)D)[f] = make_uint4(u[0], u[1], u[2], u[3]);
}

// ------------- fused value MLP via MFMA: values = tanh(tanh(X@W1+b1)@W2+b2)@wh + bh
__global__ __launch_bounds__(256) void mlp_v_kernel(
    const float* __restrict__ X, int nrows,
    const unsigned short* __restrict__ W1s, const float* __restrict__ b1,
    const unsigned short* __restrict__ W2s, const float* __restrict__ b2,
    const float* __restrict__ wh, const float* __restrict__ bh,
    float* __restrict__ outv)
{
    __shared__ unsigned short sm[16896];   // union: xs (64x136) / h1 (64x264)  33792 B
    const int tid = threadIdx.x;
    const int lane = tid & 63, wave = tid >> 6;
    const int l15 = lane & 15, quad = lane >> 4;
    const int wr0 = wave * 16;
    const int row0 = blockIdx.x * 64;

    // stage X tile 64x128 f32 -> bf16 LDS (row stride 136)
#pragma unroll
    for (int i = 0; i < 8; ++i) {
        int f = tid + i * 256;
        int rr = f >> 5, c4 = f & 31;
        float4 v = make_float4(0.f, 0.f, 0.f, 0.f);
        if (row0 + rr < nrows) v = *(const float4*)(X + (size_t)(row0 + rr) * SD + c4 * 4);
        unsigned int u0 = (unsigned int)f2bf(v.x) | ((unsigned int)f2bf(v.y) << 16);
        unsigned int u1 = (unsigned int)f2bf(v.z) | ((unsigned int)f2bf(v.w) << 16);
        *(uint2*)(sm + rr * 136 + c4 * 4) = make_uint2(u0, u1);
    }
    __syncthreads();

    f32x4 acc[16];
#pragma unroll
    for (int nt = 0; nt < 16; ++nt) acc[nt] = (f32x4){0.f, 0.f, 0.f, 0.f};

    // layer 1: K=128, 4 k-steps
    for (int ks = 0; ks < 4; ++ks) {
        short8 af = *(const short8*)(sm + (wr0 + l15) * 136 + ks * 32 + quad * 8);
#pragma unroll
        for (int nt = 0; nt < 16; ++nt) {
            short8 bf = ((const short8*)W1s)[(ks * 16 + nt) * 64 + lane];
            acc[nt] = __builtin_amdgcn_mfma_f32_16x16x32_bf16(af, bf, acc[nt], 0, 0, 0);
        }
    }
    // tanh(+bias) in regs
#pragma unroll
    for (int nt = 0; nt < 16; ++nt) {
        float bb = b1[nt * 16 + l15];
#pragma unroll
        for (int rg = 0; rg < 4; ++rg) acc[nt][rg] = tanhf(acc[nt][rg] + bb);
    }
    __syncthreads();   // all xs reads done before overwrite
#pragma unroll
    for (int nt = 0; nt < 16; ++nt)
#pragma unroll
        for (int rg = 0; rg < 4; ++rg)
            sm[(wr0 + quad * 4 + rg) * 264 + nt * 16 + l15] = f2bf(acc[nt][rg]);
    __syncthreads();

#pragma unroll
    for (int nt = 0; nt < 16; ++nt) acc[nt] = (f32x4){0.f, 0.f, 0.f, 0.f};

    // layer 2: K=256, 8 k-steps
    for (int ks = 0; ks < 8; ++ks) {
        short8 af = *(const short8*)(sm + (wr0 + l15) * 264 + ks * 32 + quad * 8);
#pragma unroll
        for (int nt = 0; nt < 16; ++nt) {
            short8 bf = ((const short8*)W2s)[(ks * 16 + nt) * 64 + lane];
            acc[nt] = __builtin_amdgcn_mfma_f32_16x16x32_bf16(af, bf, acc[nt], 0, 0, 0);
        }
    }

    // value head: per-row dot(tanh(h2), wh) reduced across the 16 col-lanes
    float vp[4] = {0.f, 0.f, 0.f, 0.f};
#pragma unroll
    for (int nt = 0; nt < 16; ++nt) {
        int col = nt * 16 + l15;
        float bb = b2[col], w = wh[col];
#pragma unroll
        for (int rg = 0; rg < 4; ++rg) vp[rg] += tanhf(acc[nt][rg] + bb) * w;
    }
#pragma unroll
    for (int off = 8; off >= 1; off >>= 1)
#pragma unroll
        for (int rg = 0; rg < 4; ++rg) vp[rg] += __shfl_xor(vp[rg], off, 16);
    if (l15 == 0) {
        float bb = bh[0];
#pragma unroll
        for (int rg = 0; rg < 4; ++rg) {
            int rr = row0 + wr0 + quad * 4 + rg;
            if (rr < nrows) outv[rr] = vp[rg] + bb;
        }
    }
}

// ------------- GAE phase 1
__global__ __launch_bounds__(256) void gae_chunk_kernel(
    const float* __restrict__ rw, const float* __restrict__ m,
    const float* __restrict__ values, float* __restrict__ delta_out,
    float* __restrict__ chunkP, float* __restrict__ chunkB)
{
    __shared__ float sp_[256], sb_[256];
    const int j = threadIdx.x;
    const int t0 = blockIdx.x * 1024 + j * 4;

    float4 vv = *(const float4*)(values + t0);
    float v4 = values[t0 + 4];
    float4 rr = *(const float4*)(rw + t0);
    float4 mm = *(const float4*)(m + t0);
    float vs[5] = {vv.x, vv.y, vv.z, vv.w, v4};
    float rs[4] = {rr.x, rr.y, rr.z, rr.w};
    float ms[4] = {mm.x, mm.y, mm.z, mm.w};
    float d[4];
#pragma unroll
    for (int i = 0; i < 4; ++i)
        d[i] = rs[i] + GAMMA * vs[i + 1] * ms[i] - vs[i];
    *(float4*)(delta_out + t0) = make_float4(d[0], d[1], d[2], d[3]);

    const float g = GAMMA * LMBDA;
    float P = 1.f, B = 0.f;
#pragma unroll
    for (int i = 3; i >= 0; --i) {
        float p = g * ms[i];
        B = d[i] + p * B;
        P = p * P;
    }
    sp_[j] = P; sb_[j] = B;
    __syncthreads();
    for (int dstep = 1; dstep < 256; dstep <<= 1) {
        float pj = sp_[j], bj = sb_[j], pk = 1.f, bk = 0.f;
        if (j + dstep < 256) { pk = sp_[j + dstep]; bk = sb_[j + dstep]; }
        __syncthreads();
        sp_[j] = pj * pk;
        sb_[j] = bj + pj * bk;
        __syncthreads();
    }
    if (j == 0) { chunkP[blockIdx.x] = sp_[0]; chunkB[blockIdx.x] = sb_[0]; }
}

// ------------- GAE phase 2
__global__ __launch_bounds__(64) void gae_carry_kernel(
    const float* __restrict__ chunkP, const float* __restrict__ chunkB,
    float* __restrict__ carry)
{
    if (threadIdx.x == 0) {
        float A = 0.f;
        for (int c = 63; c >= 0; --c) {
            carry[c] = A;
            A = chunkB[c] + chunkP[c] * A;
        }
    }
}

// ------------- GAE phase 3
__global__ __launch_bounds__(256) void gae_apply_kernel(
    const float* __restrict__ m, const float* __restrict__ delta,
    const float* __restrict__ carry,
    float* __restrict__ adv_out, float* __restrict__ scal)
{
    __shared__ float sp_[256], sb_[256];
    __shared__ float red[12];
    const int j = threadIdx.x;
    const int t0 = blockIdx.x * 1024 + j * 4;

    float4 dd = *(const float4*)(delta + t0);
    float4 mm = *(const float4*)(m + t0);
    float ds[4] = {dd.x, dd.y, dd.z, dd.w};
    float ms[4] = {mm.x, mm.y, mm.z, mm.w};
    const float g = GAMMA * LMBDA;

    float P = 1.f, B = 0.f;
#pragma unroll
    for (int i = 3; i >= 0; --i) {
        float p = g * ms[i];
        B = ds[i] + p * B;
        P = p * P;
    }
    sp_[j] = P; sb_[j] = B;
    __syncthreads();
    for (int dstep = 1; dstep < 256; dstep <<= 1) {
        float pj = sp_[j], bj = sb_[j], pk = 1.f, bk = 0.f;
        if (j + dstep < 256) { pk = sp_[j + dstep]; bk = sb_[j + dstep]; }
        __syncthreads();
        sp_[j] = pj * pk;
        sb_[j] = bj + pj * bk;
        __syncthreads();
    }
    float Pe = 1.f, Be = 0.f;
    if (j < 255) { Pe = sp_[j + 1]; Be = sb_[j + 1]; }
    float A = Be + Pe * carry[blockIdx.x];

    float s1 = 0.f, s2 = 0.f, vf = 0.f;
    float a4[4];
#pragma unroll
    for (int i = 3; i >= 0; --i) {
        A = ds[i] + g * ms[i] * A;
        a4[i] = A;
        float ab = fabsf(A);
        vf += (ab < 1.f) ? 0.5f * A * A : ab - 0.5f;
        s1 += A;
        s2 += A * A;
    }
    *(float4*)(adv_out + t0) = make_float4(a4[0], a4[1], a4[2], a4[3]);

#pragma unroll
    for (int off = 32; off >= 1; off >>= 1) {
        s1 += __shfl_down(s1, off, 64);
        s2 += __shfl_down(s2, off, 64);
        vf += __shfl_down(vf, off, 64);
    }
    if ((j & 63) == 0) {
        int w = j >> 6;
        red[w] = s1; red[4 + w] = s2; red[8 + w] = vf;
    }
    __syncthreads();
    if (j == 0) {
        atomicAdd(&scal[0], red[0] + red[1] + red[2] + red[3]);
        atomicAdd(&scal[1], red[4] + red[5] + red[6] + red[7]);
        atomicAdd(&scal[2], red[8] + red[9] + red[10] + red[11]);
    }
}

// ------------- fused policy MLP (MFMA) + mu head (MFMA) + clipped PG loss
__global__ __launch_bounds__(256) void mlp_pi_kernel(
    const float* __restrict__ X,
    const unsigned short* __restrict__ W1s, const float* __restrict__ b1,
    const unsigned short* __restrict__ W2s, const float* __restrict__ b2,
    const unsigned short* __restrict__ muWs, const float* __restrict__ mub,
    const float* __restrict__ logstd,
    const float* __restrict__ act, const float* __restrict__ lpold,
    const float* __restrict__ adv, float* __restrict__ scal)
{
    __shared__ unsigned short sm[16896];   // union xs/h1/h2
    __shared__ float mut[64 * 8];
    __shared__ float red[4];
    const int tid = threadIdx.x;
    const int lane = tid & 63, wave = tid >> 6;
    const int l15 = lane & 15, quad = lane >> 4;
    const int wr0 = wave * 16;
    const int row0 = blockIdx.x * 64;

#pragma unroll
    for (int i = 0; i < 8; ++i) {
        int f = tid + i * 256;
        int rr = f >> 5, c4 = f & 31;
        float4 v = *(const float4*)(X + (size_t)(row0 + rr) * SD + c4 * 4);
        unsigned int u0 = (unsigned int)f2bf(v.x) | ((unsigned int)f2bf(v.y) << 16);
        unsigned int u1 = (unsigned int)f2bf(v.z) | ((unsigned int)f2bf(v.w) << 16);
        *(uint2*)(sm + rr * 136 + c4 * 4) = make_uint2(u0, u1);
    }
    __syncthreads();

    f32x4 acc[16];
#pragma unroll
    for (int nt = 0; nt < 16; ++nt) acc[nt] = (f32x4){0.f, 0.f, 0.f, 0.f};

    for (int ks = 0; ks < 4; ++ks) {
        short8 af = *(const short8*)(sm + (wr0 + l15) * 136 + ks * 32 + quad * 8);
#pragma unroll
        for (int nt = 0; nt < 16; ++nt) {
            short8 bf = ((const short8*)W1s)[(ks * 16 + nt) * 64 + lane];
            acc[nt] = __builtin_amdgcn_mfma_f32_16x16x32_bf16(af, bf, acc[nt], 0, 0, 0);
        }
    }
#pragma unroll
    for (int nt = 0; nt < 16; ++nt) {
        float bb = b1[nt * 16 + l15];
#pragma unroll
        for (int rg = 0; rg < 4; ++rg) acc[nt][rg] = tanhf(acc[nt][rg] + bb);
    }
    __syncthreads();
#pragma unroll
    for (int nt = 0; nt < 16; ++nt)
#pragma unroll
        for (int rg = 0; rg < 4; ++rg)
            sm[(wr0 + quad * 4 + rg) * 264 + nt * 16 + l15] = f2bf(acc[nt][rg]);
    __syncthreads();

#pragma unroll
    for (int nt = 0; nt < 16; ++nt) acc[nt] = (f32x4){0.f, 0.f, 0.f, 0.f};

    for (int ks = 0; ks < 8; ++ks) {
        short8 af = *(const short8*)(sm + (wr0 + l15) * 264 + ks * 32 + quad * 8);
#pragma unroll
        for (int nt = 0; nt < 16; ++nt) {
            short8 bf = ((const short8*)W2s)[(ks * 16 + nt) * 64 + lane];
            acc[nt] = __builtin_amdgcn_mfma_f32_16x16x32_bf16(af, bf, acc[nt], 0, 0, 0);
        }
    }

    // h2 = tanh(.+b2) -> LDS (overwrite h1)
#pragma unroll
    for (int nt = 0; nt < 16; ++nt) {
        float bb = b2[nt * 16 + l15];
#pragma unroll
        for (int rg = 0; rg < 4; ++rg) acc[nt][rg] = tanhf(acc[nt][rg] + bb);
    }
    __syncthreads();
#pragma unroll
    for (int nt = 0; nt < 16; ++nt)
#pragma unroll
        for (int rg = 0; rg < 4; ++rg)
            sm[(wr0 + quad * 4 + rg) * 264 + nt * 16 + l15] = f2bf(acc[nt][rg]);
    __syncthreads();

    // mu head: 16x16x32 MFMA against padded muW (cols 8..15 are zero)
    f32x4 am = (f32x4){0.f, 0.f, 0.f, 0.f};
    for (int ks = 0; ks < 8; ++ks) {
        short8 af = *(const short8*)(sm + (wr0 + l15) * 264 + ks * 32 + quad * 8);
        short8 bf = ((const short8*)muWs)[ks * 64 + lane];
        am = __builtin_amdgcn_mfma_f32_16x16x32_bf16(af, bf, am, 0, 0, 0);
    }
    if (l15 < 8) {
#pragma unroll
        for (int rg = 0; rg < 4; ++rg)
            mut[(wr0 + quad * 4 + rg) * 8 + l15] = am[rg];
    }
    __syncthreads();

    const float ssum = scal[0], ssq = scal[1];
    const float meanA = ssum / (float)TH;
    const float varA = fmaxf((ssq - ssum * ssum / (float)TH) / (float)(TH - 1), 0.f);
    const float inv_denom = 1.f / (sqrtf(varA) + 1e-8f);

    float pg = 0.f;
    if (quad == 0) {
        int rl = wr0 + l15;
        int row = row0 + rl;
        const float* ar = act + (size_t)row * AD;
        float lp = 0.f;
#pragma unroll
        for (int aj = 0; aj < 8; ++aj) {
            float ls = logstd[aj];
            float mu = mut[rl * 8 + aj] + mub[aj];
            float z = (ar[aj] - mu) * expf(-ls);
            lp += -0.5f * z * z - ls;
        }
        lp -= 4.f * LOG2PI;
        float ratio = expf(lp - lpold[row]);
        float aN = (adv[row] - meanA) * inv_denom;
        float rc = fminf(fmaxf(ratio, 1.f - EPSC), 1.f + EPSC);
        pg = -fminf(ratio * aN, rc * aN);
    }
#pragma unroll
    for (int off = 32; off >= 1; off >>= 1) pg += __shfl_xor(pg, off, 64);
    if (lane == 0) red[wave] = pg;
    __syncthreads();
    if (tid == 0) atomicAdd(&scal[3], red[0] + red[1] + red[2] + red[3]);
}

__global__ __launch_bounds__(64) void finalize_kernel(
    const float* __restrict__ scal, const float* __restrict__ logstd,
    float* __restrict__ out)
{
    if (threadIdx.x == 0) {
        float ls = 0.f;
        for (int j = 0; j < AD; ++j) ls += logstd[j];
        float entropy = 0.5f + 0.5f * LOG2PI + ls / (float)AD;
        out[0] = scal[3] / (float)TH + VFC * (scal[2] / (float)TH) - ENTC * entropy;
    }
}

extern "C" void kernel_launch(void* const* d_in, const int* in_sizes, int n_in,
                              void* d_out, int out_size, void* d_ws, size_t ws_size,
                              hipStream_t stream) {
    const float* s      = (const float*)d_in[0];
    const float* a      = (const float*)d_in[1];
    const float* r      = (const float*)d_in[2];
    const float* sp     = (const float*)d_in[3];
    const float* lpold  = (const float*)d_in[4];
    const float* dmask  = (const float*)d_in[5];
    const float* piW1   = (const float*)d_in[6];
    const float* pib1   = (const float*)d_in[7];
    const float* piW2   = (const float*)d_in[8];
    const float* pib2   = (const float*)d_in[9];
    const float* muW    = (const float*)d_in[10];
    const float* mub    = (const float*)d_in[11];
    const float* logstd = (const float*)d_in[12];
    const float* vW1    = (const float*)d_in[13];
    const float* vb1    = (const float*)d_in[14];
    const float* vW2    = (const float*)d_in[15];
    const float* vb2    = (const float*)d_in[16];
    const float* vhW    = (const float*)d_in[17];
    const float* vhb    = (const float*)d_in[18];

    float* ws      = (float*)d_ws;
    float* values  = ws + WS_VALUES;
    float* adv     = ws + WS_ADV;
    float* delta   = ws + WS_DELTA;
    float* chunkP  = ws + WS_CHP;
    float* chunkB  = ws + WS_CHB;
    float* carry   = ws + WS_CARRY;
    float* scal    = ws + WS_SCAL;
    unsigned short* bfbase = (unsigned short*)(ws + WS_BF);
    unsigned short* dPiW1 = bfbase + SW_PIW1;
    unsigned short* dPiW2 = bfbase + SW_PIW2;
    unsigned short* dVW1  = bfbase + SW_VW1;
    unsigned short* dVW2  = bfbase + SW_VW2;
    unsigned short* dMuW  = bfbase + SW_MUW;

    zero_scal_kernel<<<1, 64, 0, stream>>>(scal);
    swizzle_kernel<<<98, 256, 0, stream>>>(piW1, vW1, piW2, vW2, muW,
                                           dPiW1, dVW1, dPiW2, dVW2, dMuW);

    mlp_v_kernel<<<TH / 64, 256, 0, stream>>>(s, TH, dVW1, vb1, dVW2, vb2, vhW, vhb, values);
    mlp_v_kernel<<<1, 256, 0, stream>>>(sp + (size_t)(TH - 1) * SD, 1,
                                        dVW1, vb1, dVW2, vb2, vhW, vhb, values + TH);

    gae_chunk_kernel<<<64, 256, 0, stream>>>(r, dmask, values, delta, chunkP, chunkB);
    gae_carry_kernel<<<1, 64, 0, stream>>>(chunkP, chunkB, carry);
    gae_apply_kernel<<<64, 256, 0, stream>>>(dmask, delta, carry, adv, scal);

    mlp_pi_kernel<<<TH / 64, 256, 0, stream>>>(s, dPiW1, pib1, dPiW2, pib2,
                                               dMuW, mub, logstd, a, lpold, adv, scal);

    finalize_kernel<<<1, 64, 0, stream>>>(scal, logstd, (float*)d_out);
}

// Round 3
// 207.064 us; speedup vs baseline: 2.9130x; 1.9709x over previous
//
#include <hip/hip_runtime.h>
#include <math.h>

#define TH 65536
#define SD 128
#define AD 8
#define HD 256

constexpr float GAMMA  = 0.99f;
constexpr float LMBDA  = 0.95f;
constexpr float EPSC   = 0.2f;
constexpr float VFC    = 0.5f;
constexpr float ENTC   = 0.01f;
constexpr float LOG2PI = 1.8378770664093453f;

typedef __attribute__((ext_vector_type(8))) short short8;
typedef __attribute__((ext_vector_type(4))) float f32x4;

// workspace layout (float offsets)
constexpr size_t WS_VALUES = 0;        // TH+1 (reserve 65540)
constexpr size_t WS_ADV    = 65540;    // TH
constexpr size_t WS_RATIO  = 131080;   // TH
constexpr size_t WS_CHP    = 196616;   // 64
constexpr size_t WS_CHB    = 196680;   // 64
constexpr size_t WS_CARRY  = 196744;   // 64
constexpr size_t WS_SCAL   = 196808;   // 8: [0]sum [1]sumsq [2]vf [3]pg [4]ticket
constexpr size_t WS_BF     = 196816;   // bf16 weights (ushort offsets below)
constexpr size_t SW_PIW1 = 0;          // 4*16*64*8  = 32768
constexpr size_t SW_PIW2 = 32768;      // 8*16*64*8  = 65536
constexpr size_t SW_VW1  = 98304;      // 32768
constexpr size_t SW_VW2  = 131072;     // 65536 -> total 196608 ushorts

__device__ __forceinline__ unsigned short f2bf(float x) {
    unsigned int u = __float_as_uint(x);
    unsigned int r = (u + 0x7fffu + ((u >> 16) & 1u)) >> 16;
    return (unsigned short)r;
}

// fast tanh: clamp + exp + hw rcp (~7 VALU ops vs ~30 for libm tanhf)
__device__ __forceinline__ float ftanh(float x) {
    float cx = fminf(fmaxf(x, -9.f), 9.f);
    float e = __expf(cx + cx);
    return (e - 1.f) * __builtin_amdgcn_rcpf(e + 1.f);
}

// ------------- weight swizzle (+ scalar zeroing in block 0)
// frag id f: lane=f&63, grp=f>>6, nt=grp%16, ks=grp/16
// elem j: k = ks*32 + (lane>>4)*8 + j, n = nt*16 + (lane&15)
__global__ __launch_bounds__(256) void swizzle_kernel(
    const float* __restrict__ piW1, const float* __restrict__ vW1,
    const float* __restrict__ piW2, const float* __restrict__ vW2,
    unsigned short* __restrict__ dPiW1, unsigned short* __restrict__ dVW1,
    unsigned short* __restrict__ dPiW2, unsigned short* __restrict__ dVW2,
    float* __restrict__ scal)
{
    if (blockIdx.x == 0 && threadIdx.x < 8) scal[threadIdx.x] = 0.f;
    int fid = blockIdx.x * 256 + threadIdx.x;
    const float* S; unsigned short* D; int lo;
    if      (fid <  4096) { S = piW1; D = dPiW1; lo = 0;     }
    else if (fid <  8192) { S = vW1;  D = dVW1;  lo = 4096;  }
    else if (fid < 16384) { S = piW2; D = dPiW2; lo = 8192;  }
    else                  { S = vW2;  D = dVW2;  lo = 16384; }
    int f = fid - lo;
    int lane = f & 63, grp = f >> 6;
    int nt = grp % 16, ks = grp / 16;
    int k0 = ks * 32 + ((lane >> 4) << 3);
    int n  = nt * 16 + (lane & 15);
    unsigned int u[4];
#pragma unroll
    for (int jj = 0; jj < 4; ++jj) {
        float v0 = S[(size_t)(k0 + 2 * jj) * HD + n];
        float v1 = S[(size_t)(k0 + 2 * jj + 1) * HD + n];
        u[jj] = (unsigned int)f2bf(v0) | ((unsigned int)f2bf(v1) << 16);
    }
    ((uint4*)D)[f] = make_uint4(u[0], u[1], u[2], u[3]);
}

// one MLP layer for a 16x128 wave tile (8 col-tiles), A from LDS, B swizzled from global
template <int NKS, int ASTRIDE>
__device__ __forceinline__ void runlayer(
    f32x4* acc, const unsigned short* __restrict__ Ws,
    const unsigned short* ab, int l15, int quad, int rowgrp, int colhalf, int lane)
{
#pragma unroll
    for (int nt = 0; nt < 8; ++nt) acc[nt] = (f32x4){0.f, 0.f, 0.f, 0.f};
#pragma unroll
    for (int ks = 0; ks < NKS; ++ks) {
        short8 af = *(const short8*)(ab + (rowgrp * 16 + l15) * ASTRIDE + ks * 32 + quad * 8);
#pragma unroll
        for (int ntl = 0; ntl < 8; ++ntl) {
            short8 bf = ((const short8*)Ws)[(ks * 16 + colhalf * 8 + ntl) * 64 + lane];
            acc[ntl] = __builtin_amdgcn_mfma_f32_16x16x32_bf16(af, bf, acc[ntl], 0, 0, 0);
        }
    }
}

// ------------- fused pi+v MLP: per 32-row tile computes ratio[] (pi) and values[] (v)
__global__ __launch_bounds__(256, 3) void mlp_fused_kernel(
    const float* __restrict__ X, const float* __restrict__ Xlast,
    const unsigned short* __restrict__ piW1s, const float* __restrict__ pib1,
    const unsigned short* __restrict__ piW2s, const float* __restrict__ pib2,
    const float* __restrict__ muW, const float* __restrict__ mub,
    const float* __restrict__ logstd,
    const float* __restrict__ act, const float* __restrict__ lpold,
    const unsigned short* __restrict__ vW1s, const float* __restrict__ vb1,
    const unsigned short* __restrict__ vW2s, const float* __restrict__ vb2,
    const float* __restrict__ vhW, const float* __restrict__ vhb,
    float* __restrict__ values, float* __restrict__ ratio)
{
    __shared__ unsigned short xs[32 * 136];   // 8704 B
    __shared__ unsigned short h1[32 * 264];   // 16896 B
    __shared__ float cmb[2][32][8];           // 2048 B (mu partials / value partials)
    const int tid = threadIdx.x;
    const int lane = tid & 63, wave = tid >> 6;
    const int l15 = lane & 15, quad = lane >> 4;
    const int rowgrp = wave >> 1, colhalf = wave & 1;
    const bool vonly = (blockIdx.x == gridDim.x - 1);
    const float* Xp = vonly ? Xlast : X + (size_t)blockIdx.x * 32 * SD;
    const int nrows = vonly ? 1 : 32;
    const int vout0 = vonly ? TH : blockIdx.x * 32;

    // stage 32x128 f32 -> bf16 LDS (row stride 136 ushorts)
#pragma unroll
    for (int i = 0; i < 4; ++i) {
        int f = tid + i * 256;
        int rr = f >> 5, c4 = f & 31;
        float4 v = make_float4(0.f, 0.f, 0.f, 0.f);
        if (rr < nrows) v = *(const float4*)(Xp + (size_t)rr * SD + c4 * 4);
        unsigned int u0 = (unsigned int)f2bf(v.x) | ((unsigned int)f2bf(v.y) << 16);
        unsigned int u1 = (unsigned int)f2bf(v.z) | ((unsigned int)f2bf(v.w) << 16);
        *(uint2*)(xs + rr * 136 + c4 * 4) = make_uint2(u0, u1);
    }
    __syncthreads();

    f32x4 acc[8];

    if (!vonly) {
        // ---- pi layer 1
        runlayer<4, 136>(acc, piW1s, xs, l15, quad, rowgrp, colhalf, lane);
#pragma unroll
        for (int ntl = 0; ntl < 8; ++ntl) {
            int col = (colhalf * 8 + ntl) * 16 + l15;
            float bb = pib1[col];
#pragma unroll
            for (int rg = 0; rg < 4; ++rg)
                h1[(rowgrp * 16 + quad * 4 + rg) * 264 + col] = f2bf(ftanh(acc[ntl][rg] + bb));
        }
        __syncthreads();
        // ---- pi layer 2
        runlayer<8, 264>(acc, piW2s, h1, l15, quad, rowgrp, colhalf, lane);
        // ---- mu head partials (VALU dot over this wave's 8 cols)
        float pm[4][8];
#pragma unroll
        for (int rg = 0; rg < 4; ++rg)
#pragma unroll
            for (int aj = 0; aj < 8; ++aj) pm[rg][aj] = 0.f;
#pragma unroll
        for (int ntl = 0; ntl < 8; ++ntl) {
            int col = (colhalf * 8 + ntl) * 16 + l15;
            float bb = pib2[col];
            float4 w0 = *(const float4*)(muW + (size_t)col * AD);
            float4 w1 = *(const float4*)(muW + (size_t)col * AD + 4);
            float wv[8] = {w0.x, w0.y, w0.z, w0.w, w1.x, w1.y, w1.z, w1.w};
#pragma unroll
            for (int rg = 0; rg < 4; ++rg) {
                float hv = ftanh(acc[ntl][rg] + bb);
#pragma unroll
                for (int aj = 0; aj < 8; ++aj) pm[rg][aj] = fmaf(hv, wv[aj], pm[rg][aj]);
            }
        }
#pragma unroll
        for (int off = 8; off >= 1; off >>= 1)
#pragma unroll
            for (int rg = 0; rg < 4; ++rg)
#pragma unroll
                for (int aj = 0; aj < 8; ++aj)
                    pm[rg][aj] += __shfl_xor(pm[rg][aj], off, 16);
        if (l15 == 0) {
#pragma unroll
            for (int rg = 0; rg < 4; ++rg) {
                *(float4*)&cmb[colhalf][rowgrp * 16 + quad * 4 + rg][0] =
                    make_float4(pm[rg][0], pm[rg][1], pm[rg][2], pm[rg][3]);
                *(float4*)&cmb[colhalf][rowgrp * 16 + quad * 4 + rg][4] =
                    make_float4(pm[rg][4], pm[rg][5], pm[rg][6], pm[rg][7]);
            }
        }
        __syncthreads();
        // ---- per-row log-prob ratio
        if (tid < 32) {
            int row = blockIdx.x * 32 + tid;
            const float* ar = act + (size_t)row * AD;
            float lp = 0.f;
#pragma unroll
            for (int aj = 0; aj < 8; ++aj) {
                float ls = logstd[aj];
                float mu = cmb[0][tid][aj] + cmb[1][tid][aj] + mub[aj];
                float z = (ar[aj] - mu) * __expf(-ls);
                lp += -0.5f * z * z - ls;
            }
            lp -= 4.f * LOG2PI;
            ratio[row] = __expf(lp - lpold[row]);
        }
    }

    // ---- v layer 1 (xs still intact; h1 reads of pi layer2 are barrier-ordered)
    runlayer<4, 136>(acc, vW1s, xs, l15, quad, rowgrp, colhalf, lane);
#pragma unroll
    for (int ntl = 0; ntl < 8; ++ntl) {
        int col = (colhalf * 8 + ntl) * 16 + l15;
        float bb = vb1[col];
#pragma unroll
        for (int rg = 0; rg < 4; ++rg)
            h1[(rowgrp * 16 + quad * 4 + rg) * 264 + col] = f2bf(ftanh(acc[ntl][rg] + bb));
    }
    __syncthreads();
    // ---- v layer 2 + value head
    runlayer<8, 264>(acc, vW2s, h1, l15, quad, rowgrp, colhalf, lane);
    float vp[4] = {0.f, 0.f, 0.f, 0.f};
#pragma unroll
    for (int ntl = 0; ntl < 8; ++ntl) {
        int col = (colhalf * 8 + ntl) * 16 + l15;
        float bb = vb2[col], w = vhW[col];
#pragma unroll
        for (int rg = 0; rg < 4; ++rg) vp[rg] += ftanh(acc[ntl][rg] + bb) * w;
    }
#pragma unroll
    for (int off = 8; off >= 1; off >>= 1)
#pragma unroll
        for (int rg = 0; rg < 4; ++rg) vp[rg] += __shfl_xor(vp[rg], off, 16);
    if (l15 == 0) {
#pragma unroll
        for (int rg = 0; rg < 4; ++rg)
            cmb[colhalf][rowgrp * 16 + quad * 4 + rg][0] = vp[rg];
    }
    __syncthreads();
    if (tid < nrows)
        values[vout0 + tid] = cmb[0][tid][0] + cmb[1][tid][0] + vhb[0];
}

// ------------- GAE phase 1: per-chunk affine composition (deltas recomputed on the fly)
__global__ __launch_bounds__(256) void gae_chunk_kernel(
    const float* __restrict__ rw, const float* __restrict__ m,
    const float* __restrict__ values,
    float* __restrict__ chunkP, float* __restrict__ chunkB)
{
    __shared__ float sp_[256], sb_[256];
    const int j = threadIdx.x;
    const int t0 = blockIdx.x * 1024 + j * 4;

    float4 vv = *(const float4*)(values + t0);
    float v4 = values[t0 + 4];
    float4 rr = *(const float4*)(rw + t0);
    float4 mm = *(const float4*)(m + t0);
    float vs[5] = {vv.x, vv.y, vv.z, vv.w, v4};
    float rs[4] = {rr.x, rr.y, rr.z, rr.w};
    float ms[4] = {mm.x, mm.y, mm.z, mm.w};
    float d[4];
#pragma unroll
    for (int i = 0; i < 4; ++i)
        d[i] = rs[i] + GAMMA * vs[i + 1] * ms[i] - vs[i];

    const float g = GAMMA * LMBDA;
    float P = 1.f, B = 0.f;
#pragma unroll
    for (int i = 3; i >= 0; --i) {
        float p = g * ms[i];
        B = d[i] + p * B;
        P = p * P;
    }
    sp_[j] = P; sb_[j] = B;
    __syncthreads();
    for (int dstep = 1; dstep < 256; dstep <<= 1) {
        float pj = sp_[j], bj = sb_[j], pk = 1.f, bk = 0.f;
        if (j + dstep < 256) { pk = sp_[j + dstep]; bk = sb_[j + dstep]; }
        __syncthreads();
        sp_[j] = pj * pk;
        sb_[j] = bj + pj * bk;
        __syncthreads();
    }
    if (j == 0) { chunkP[blockIdx.x] = sp_[0]; chunkB[blockIdx.x] = sb_[0]; }
}

// ------------- GAE phase 2: serial carry over 64 chunks
__global__ __launch_bounds__(64) void gae_carry_kernel(
    const float* __restrict__ chunkP, const float* __restrict__ chunkB,
    float* __restrict__ carry)
{
    if (threadIdx.x == 0) {
        float A = 0.f;
        for (int c = 63; c >= 0; --c) {
            carry[c] = A;
            A = chunkB[c] + chunkP[c] * A;
        }
    }
}

// ------------- GAE phase 3: apply carries, emit adv + sum/sumsq/vf reductions
__global__ __launch_bounds__(256) void gae_apply_kernel(
    const float* __restrict__ rw, const float* __restrict__ m,
    const float* __restrict__ values, const float* __restrict__ carry,
    float* __restrict__ adv_out, float* __restrict__ scal)
{
    __shared__ float sp_[256], sb_[256];
    __shared__ float red[12];
    const int j = threadIdx.x;
    const int t0 = blockIdx.x * 1024 + j * 4;

    float4 vv = *(const float4*)(values + t0);
    float v4 = values[t0 + 4];
    float4 rr = *(const float4*)(rw + t0);
    float4 mm = *(const float4*)(m + t0);
    float vs[5] = {vv.x, vv.y, vv.z, vv.w, v4};
    float rs[4] = {rr.x, rr.y, rr.z, rr.w};
    float ms[4] = {mm.x, mm.y, mm.z, mm.w};
    float ds[4];
#pragma unroll
    for (int i = 0; i < 4; ++i)
        ds[i] = rs[i] + GAMMA * vs[i + 1] * ms[i] - vs[i];
    const float g = GAMMA * LMBDA;

    float P = 1.f, B = 0.f;
#pragma unroll
    for (int i = 3; i >= 0; --i) {
        float p = g * ms[i];
        B = ds[i] + p * B;
        P = p * P;
    }
    sp_[j] = P; sb_[j] = B;
    __syncthreads();
    for (int dstep = 1; dstep < 256; dstep <<= 1) {
        float pj = sp_[j], bj = sb_[j], pk = 1.f, bk = 0.f;
        if (j + dstep < 256) { pk = sp_[j + dstep]; bk = sb_[j + dstep]; }
        __syncthreads();
        sp_[j] = pj * pk;
        sb_[j] = bj + pj * bk;
        __syncthreads();
    }
    float Pe = 1.f, Be = 0.f;
    if (j < 255) { Pe = sp_[j + 1]; Be = sb_[j + 1]; }
    float A = Be + Pe * carry[blockIdx.x];

    float s1 = 0.f, s2 = 0.f, vf = 0.f;
    float a4[4];
#pragma unroll
    for (int i = 3; i >= 0; --i) {
        A = ds[i] + g * ms[i] * A;
        a4[i] = A;
        float ab = fabsf(A);
        vf += (ab < 1.f) ? 0.5f * A * A : ab - 0.5f;   // huber(v-ret) == huber(-adv) == huber(adv)
        s1 += A;
        s2 += A * A;
    }
    *(float4*)(adv_out + t0) = make_float4(a4[0], a4[1], a4[2], a4[3]);

#pragma unroll
    for (int off = 32; off >= 1; off >>= 1) {
        s1 += __shfl_down(s1, off, 64);
        s2 += __shfl_down(s2, off, 64);
        vf += __shfl_down(vf, off, 64);
    }
    if ((j & 63) == 0) {
        int w = j >> 6;
        red[w] = s1; red[4 + w] = s2; red[8 + w] = vf;
    }
    __syncthreads();
    if (j == 0) {
        atomicAdd(&scal[0], red[0] + red[1] + red[2] + red[3]);
        atomicAdd(&scal[1], red[4] + red[5] + red[6] + red[7]);
        atomicAdd(&scal[2], red[8] + red[9] + red[10] + red[11]);
    }
}

// ------------- final: clipped PG from ratio+adv, last block writes the loss
__global__ __launch_bounds__(256) void pg_final_kernel(
    const float* __restrict__ ratio, const float* __restrict__ adv,
    float* __restrict__ scal, const float* __restrict__ logstd,
    float* __restrict__ out)
{
    __shared__ float red[4];
    const int tid = threadIdx.x;
    const int t0 = blockIdx.x * 1024 + tid * 4;

    const float ssum = scal[0], ssq = scal[1];
    const float meanA = ssum / (float)TH;
    const float varA = fmaxf((ssq - ssum * ssum / (float)TH) / (float)(TH - 1), 0.f);
    const float inv = 1.f / (sqrtf(varA) + 1e-8f);

    float4 a4 = *(const float4*)(adv + t0);
    float4 r4 = *(const float4*)(ratio + t0);
    float as[4] = {a4.x, a4.y, a4.z, a4.w};
    float rs[4] = {r4.x, r4.y, r4.z, r4.w};
    float pg = 0.f;
#pragma unroll
    for (int i = 0; i < 4; ++i) {
        float aN = (as[i] - meanA) * inv;
        float rc = fminf(fmaxf(rs[i], 1.f - EPSC), 1.f + EPSC);
        pg -= fminf(rs[i] * aN, rc * aN);
    }
#pragma unroll
    for (int off = 32; off >= 1; off >>= 1) pg += __shfl_down(pg, off, 64);
    if ((tid & 63) == 0) red[tid >> 6] = pg;
    __syncthreads();
    if (tid == 0) {
        atomicAdd(&scal[3], red[0] + red[1] + red[2] + red[3]);
        __threadfence();
        float old = atomicAdd(&scal[4], 1.f);
        if (old == 63.f) {           // last block: all pg partials visible
            float pgs = atomicAdd(&scal[3], 0.f);
            float vfs = atomicAdd(&scal[2], 0.f);
            float ls = 0.f;
#pragma unroll
            for (int jj = 0; jj < AD; ++jj) ls += logstd[jj];
            float entropy = 0.5f + 0.5f * LOG2PI + ls / (float)AD;
            out[0] = pgs / (float)TH + VFC * (vfs / (float)TH) - ENTC * entropy;
        }
    }
}

extern "C" void kernel_launch(void* const* d_in, const int* in_sizes, int n_in,
                              void* d_out, int out_size, void* d_ws, size_t ws_size,
                              hipStream_t stream) {
    const float* s      = (const float*)d_in[0];
    const float* a      = (const float*)d_in[1];
    const float* r      = (const float*)d_in[2];
    const float* sp     = (const float*)d_in[3];
    const float* lpold  = (const float*)d_in[4];
    const float* dmask  = (const float*)d_in[5];
    const float* piW1   = (const float*)d_in[6];
    const float* pib1   = (const float*)d_in[7];
    const float* piW2   = (const float*)d_in[8];
    const float* pib2   = (const float*)d_in[9];
    const float* muW    = (const float*)d_in[10];
    const float* mub    = (const float*)d_in[11];
    const float* logstd = (const float*)d_in[12];
    const float* vW1    = (const float*)d_in[13];
    const float* vb1    = (const float*)d_in[14];
    const float* vW2    = (const float*)d_in[15];
    const float* vb2    = (const float*)d_in[16];
    const float* vhW    = (const float*)d_in[17];
    const float* vhb    = (const float*)d_in[18];

    float* ws      = (float*)d_ws;
    float* values  = ws + WS_VALUES;
    float* adv     = ws + WS_ADV;
    float* ratio   = ws + WS_RATIO;
    float* chunkP  = ws + WS_CHP;
    float* chunkB  = ws + WS_CHB;
    float* carry   = ws + WS_CARRY;
    float* scal    = ws + WS_SCAL;
    unsigned short* bfbase = (unsigned short*)(ws + WS_BF);
    unsigned short* dPiW1 = bfbase + SW_PIW1;
    unsigned short* dPiW2 = bfbase + SW_PIW2;
    unsigned short* dVW1  = bfbase + SW_VW1;
    unsigned short* dVW2  = bfbase + SW_VW2;

    swizzle_kernel<<<96, 256, 0, stream>>>(piW1, vW1, piW2, vW2,
                                           dPiW1, dVW1, dPiW2, dVW2, scal);

    mlp_fused_kernel<<<TH / 32 + 1, 256, 0, stream>>>(
        s, sp + (size_t)(TH - 1) * SD,
        dPiW1, pib1, dPiW2, pib2, muW, mub, logstd, a, lpold,
        dVW1, vb1, dVW2, vb2, vhW, vhb,
        values, ratio);

    gae_chunk_kernel<<<64, 256, 0, stream>>>(r, dmask, values, chunkP, chunkB);
    gae_carry_kernel<<<1, 64, 0, stream>>>(chunkP, chunkB, carry);
    gae_apply_kernel<<<64, 256, 0, stream>>>(r, dmask, values, carry, adv, scal);

    pg_final_kernel<<<64, 256, 0, stream>>>(ratio, adv, scal, logstd, (float*)d_out);
}